// Round 1
// baseline (5515.545 us; speedup 1.0000x reference)
//
#include <hip/hip_runtime.h>
#include <math.h>

// L=4, H=1024, NH=16, HD=64, FF=4096, B=4, S=1024
// ws layout (~129 MB): h fp32 16MB | qkv fp32 48MB | xb bf16 8MB | ffb bf16 32MB |
//   wqT 6MB | woT 2MB | wfT 8MB | wpT 8MB | maskf 16KB | pid 16KB

typedef unsigned short u16;
typedef unsigned int u32;
typedef __attribute__((ext_vector_type(8))) short short8;
typedef __attribute__((ext_vector_type(4))) float f32x4;
typedef __attribute__((ext_vector_type(4))) u16 u16x4;

#define NEGV (-3.402823466e38f)

__device__ __forceinline__ u16 f2bf(float f) {
  union { float f; u32 u; } v; v.f = f;
  u32 r = v.u + 0x7FFFu + ((v.u >> 16) & 1u);
  return (u16)(r >> 16);
}

__device__ __forceinline__ float gelu_tanh(float x) {
  float z = 0.7978845608028654f * (x + 0.044715f * x * x * x);
  z = fmaxf(fminf(z, 30.f), -30.f);
  float t = __expf(2.f * z);
  return 0.5f * x * (1.f + (t - 1.f) / (t + 1.f));
}

// ---------------- mask / position ids ----------------
__global__ __launch_bounds__(1024) void mask_pid_kernel(const void* __restrict__ maskp,
                                                        float* __restrict__ maskf,
                                                        int* __restrict__ pid) {
  int b = blockIdx.x, s = threadIdx.x;
  // attention_mask may be stored as 1-byte bool or int32; probe first word.
  const u32* wp = (const u32*)maskp;
  bool int_mode = ((wp[0] & 0xFFFFFF00u) == 0u);
  int mv;
  if (int_mode) mv = (((const int*)maskp)[b * 1024 + s] != 0) ? 1 : 0;
  else          mv = (((const unsigned char*)maskp)[b * 1024 + s] != 0) ? 1 : 0;
  __shared__ int sc[1024];
  sc[s] = mv;
  __syncthreads();
  for (int off = 1; off < 1024; off <<= 1) {
    int add = (s >= off) ? sc[s - off] : 0;
    __syncthreads();
    sc[s] += add;
    __syncthreads();
  }
  pid[b * 1024 + s] = mv ? (sc[s] - 1) : 0;
  maskf[b * 1024 + s] = (float)mv;
}

// ---------------- h = embeds * maskf ----------------
__global__ __launch_bounds__(256) void embed_kernel(const float* __restrict__ e,
                                                    const float* __restrict__ maskf,
                                                    float* __restrict__ h) {
  int idx = blockIdx.x * 256 + threadIdx.x;  // one float4 per thread
  size_t o = (size_t)idx * 4;
  int row = (int)(o >> 10);
  float mf = maskf[row];
  float4 v = *(const float4*)(e + o);
  float4 r; r.x = v.x * mf; r.y = v.y * mf; r.z = v.z * mf; r.w = v.w * mf;
  *(float4*)(h + o) = r;
}

// ---------------- transpose fp32 [K][N] -> bf16 [N][K] ----------------
__global__ __launch_bounds__(256) void transpose_bf16(const float* __restrict__ in,
                                                      u16* __restrict__ out,
                                                      int K, int N) {
  __shared__ float t[32][33];
  int tx = threadIdx.x, ty = threadIdx.y;
  int n0 = blockIdx.x * 32, k0 = blockIdx.y * 32;
#pragma unroll
  for (int j = 0; j < 4; ++j) {
    int k = ty + j * 8;
    t[k][tx] = in[(size_t)(k0 + k) * N + n0 + tx];
  }
  __syncthreads();
#pragma unroll
  for (int j = 0; j < 4; ++j) {
    int n = ty + j * 8;
    out[(size_t)(n0 + n) * K + k0 + tx] = f2bf(t[tx][n]);
  }
}

// ---------------- layernorm (H=1024), MODE 0: bf16 out; MODE 1: fp32*maskf out --------
template <int MODE>
__global__ __launch_bounds__(256) void ln_kernel(const float* __restrict__ x,
                                                 const float* __restrict__ g,
                                                 const float* __restrict__ bb,
                                                 u16* __restrict__ yb,
                                                 float* __restrict__ yf,
                                                 const float* __restrict__ maskf) {
  int row = blockIdx.x, tid = threadIdx.x;
  const float* xr = x + (size_t)row * 1024;
  float4 v = *(const float4*)(xr + tid * 4);
  float s = v.x + v.y + v.z + v.w;
  float q = v.x * v.x + v.y * v.y + v.z * v.z + v.w * v.w;
#pragma unroll
  for (int off = 32; off >= 1; off >>= 1) {
    s += __shfl_xor(s, off);
    q += __shfl_xor(q, off);
  }
  __shared__ float ps[4], pq[4];
  int w = tid >> 6, lane = tid & 63;
  if (lane == 0) { ps[w] = s; pq[w] = q; }
  __syncthreads();
  float S = ps[0] + ps[1] + ps[2] + ps[3];
  float Q = pq[0] + pq[1] + pq[2] + pq[3];
  float mean = S * (1.f / 1024.f);
  float var = fmaxf(Q * (1.f / 1024.f) - mean * mean, 0.f);
  float rstd = rsqrtf(var + 1e-5f);
  int c = tid * 4;
  float4 gv = *(const float4*)(g + c);
  float4 bv = *(const float4*)(bb + c);
  float y0 = (v.x - mean) * rstd * gv.x + bv.x;
  float y1 = (v.y - mean) * rstd * gv.y + bv.y;
  float y2 = (v.z - mean) * rstd * gv.z + bv.z;
  float y3 = (v.w - mean) * rstd * gv.w + bv.w;
  if (MODE == 0) {
    u16x4 o; o.x = f2bf(y0); o.y = f2bf(y1); o.z = f2bf(y2); o.w = f2bf(y3);
    *(u16x4*)(yb + (size_t)row * 1024 + c) = o;
  } else {
    float mf = maskf[row];
    float4 o; o.x = y0 * mf; o.y = y1 * mf; o.z = y2 * mf; o.w = y3 * mf;
    *(float4*)(yf + (size_t)row * 1024 + c) = o;
  }
}

// ---------------- bf16 MFMA GEMM: C[M,N] = A[M,K] @ Bt[N,K]^T + bias ----------------
// EPI 0: Of = acc+bias (fp32)
// EPI 1: Of += acc+bias (residual)
// EPI 2: Ob = bf16(gelu(acc+bias))
// EPI 3: Of = (Of + acc+bias) * maskf[row]
template <int EPI>
__global__ __launch_bounds__(256) void gemm_bf16(const u16* __restrict__ A,
                                                 const u16* __restrict__ Bt,
                                                 const float* __restrict__ bias,
                                                 float* __restrict__ Of,
                                                 u16* __restrict__ Ob,
                                                 const float* __restrict__ maskf,
                                                 int M, int N, int K) {
  __shared__ __align__(16) u16 As[64][40];
  __shared__ __align__(16) u16 Bs[64][40];
  const int tid = threadIdx.x;
  const int lane = tid & 63, w = tid >> 6;
  const int wm = w >> 1, wn = w & 1;
  const int m0 = blockIdx.y * 64, n0 = blockIdx.x * 64;
  const int lm = lane & 15, lq = lane >> 4;

  f32x4 acc[2][2] = {};
  const int r = tid >> 2;
  const int cg = (tid & 3) * 8;
  const u16* Ap = A + (size_t)(m0 + r) * K + cg;
  const u16* Bp = Bt + (size_t)(n0 + r) * K + cg;

  for (int k0 = 0; k0 < K; k0 += 32) {
    uint4 av = *(const uint4*)(Ap + k0);
    uint4 bv = *(const uint4*)(Bp + k0);
    *(uint4*)(&As[r][cg]) = av;
    *(uint4*)(&Bs[r][cg]) = bv;
    __syncthreads();
    short8 af[2], bf[2];
    af[0] = *(const short8*)(&As[wm * 32 + lm][lq * 8]);
    af[1] = *(const short8*)(&As[wm * 32 + 16 + lm][lq * 8]);
    bf[0] = *(const short8*)(&Bs[wn * 32 + lm][lq * 8]);
    bf[1] = *(const short8*)(&Bs[wn * 32 + 16 + lm][lq * 8]);
#pragma unroll
    for (int mt = 0; mt < 2; ++mt)
#pragma unroll
      for (int nt = 0; nt < 2; ++nt)
        acc[mt][nt] = __builtin_amdgcn_mfma_f32_16x16x32_bf16(af[mt], bf[nt], acc[mt][nt], 0, 0, 0);
    __syncthreads();
  }

#pragma unroll
  for (int mt = 0; mt < 2; ++mt) {
#pragma unroll
    for (int nt = 0; nt < 2; ++nt) {
      int col = n0 + wn * 32 + nt * 16 + lm;
      float bvv = bias[col];
#pragma unroll
      for (int rr = 0; rr < 4; ++rr) {
        int row = m0 + wm * 32 + mt * 16 + lq * 4 + rr;
        size_t idx = (size_t)row * N + col;
        float v = acc[mt][nt][rr] + bvv;
        if (EPI == 0) {
          Of[idx] = v;
        } else if (EPI == 1) {
          Of[idx] += v;
        } else if (EPI == 2) {
          Ob[idx] = f2bf(gelu_tanh(v));
        } else {
          Of[idx] = (Of[idx] + v) * maskf[row];
        }
      }
    }
  }
}

// ---------------- RoPE in-place on q,k of qkv fp32 [4096][3072] ----------------
__global__ __launch_bounds__(256) void rope_kernel(float* __restrict__ qkv,
                                                   const int* __restrict__ pid) {
  int idx = blockIdx.x * 256 + threadIdx.x;  // 4096*16*32
  int i = idx & 31;
  int hh = (idx >> 5) & 15;
  int row = idx >> 9;
  float p = (float)pid[row];
  // inv_freq = 10000^(-2i/64)
  float inv = __expf(-(float)(2 * i) * (9.210340371976184f / 64.f));
  float th = p * inv;
  float c = cosf(th), sn = sinf(th);
  size_t base = (size_t)row * 3072 + hh * 64 + 2 * i;
  float q0 = qkv[base], q1 = qkv[base + 1];
  qkv[base]     = q0 * c - q1 * sn;
  qkv[base + 1] = q1 * c + q0 * sn;
  float k0 = qkv[base + 1024], k1 = qkv[base + 1025];
  qkv[base + 1024] = k0 * c - k1 * sn;
  qkv[base + 1025] = k1 * c + k0 * sn;
}

// ---------------- flash attention (fp32 vector), ctx out bf16 ----------------
__global__ __launch_bounds__(256) void attn_kernel(const float* __restrict__ qkv,
                                                   const float* __restrict__ maskf,
                                                   u16* __restrict__ ctx) {
  const int b = blockIdx.z, hh = blockIdx.y, qt = blockIdx.x;
  const int q0 = qt * 64;
  const int tid = threadIdx.x;
  const int lane = tid & 63, w = tid >> 6;
  __shared__ float Qs[64][65];
  __shared__ float Ks[64][65];
  __shared__ float Vs[64][65];
  __shared__ float Ps[4][64];

  const int r = tid >> 2;
  const int cc = (tid & 3) * 16;
  {
    const float* qb = qkv + (size_t)(b * 1024 + q0 + r) * 3072 + hh * 64 + cc;
#pragma unroll
    for (int u = 0; u < 16; u += 4) {
      float4 qv = *(const float4*)(qb + u);
      Qs[r][cc + u + 0] = qv.x * 0.125f;
      Qs[r][cc + u + 1] = qv.y * 0.125f;
      Qs[r][cc + u + 2] = qv.z * 0.125f;
      Qs[r][cc + u + 3] = qv.w * 0.125f;
    }
  }

  float m_i[16], l_i[16], o_i[16];
#pragma unroll
  for (int i = 0; i < 16; ++i) { m_i[i] = -INFINITY; l_i[i] = 0.f; o_i[i] = 0.f; }

  const int ntiles = qt + 1;
  for (int t = 0; t < ntiles; ++t) {
    __syncthreads();
    {
      const float* kb = qkv + (size_t)(b * 1024 + t * 64 + r) * 3072 + 1024 + hh * 64 + cc;
      const float* vb = kb + 1024;
#pragma unroll
      for (int u = 0; u < 16; u += 4) {
        float4 kv = *(const float4*)(kb + u);
        float4 vv = *(const float4*)(vb + u);
        Ks[r][cc + u + 0] = kv.x; Ks[r][cc + u + 1] = kv.y;
        Ks[r][cc + u + 2] = kv.z; Ks[r][cc + u + 3] = kv.w;
        Vs[r][cc + u + 0] = vv.x; Vs[r][cc + u + 1] = vv.y;
        Vs[r][cc + u + 2] = vv.z; Vs[r][cc + u + 3] = vv.w;
      }
    }
    __syncthreads();
    const int kk = t * 64 + lane;
    const float kmask = maskf[b * 1024 + kk];
#pragma unroll 1
    for (int i = 0; i < 16; ++i) {
      const int qlr = w * 16 + i;
      const int qr = q0 + qlr;
      float s = 0.f;
#pragma unroll
      for (int d = 0; d < 64; ++d) s = fmaf(Qs[qlr][d], Ks[lane][d], s);
      bool valid = (kk <= qr) && (kmask != 0.f);
      s = valid ? s : NEGV;
      float mt_ = s;
#pragma unroll
      for (int off = 32; off >= 1; off >>= 1) mt_ = fmaxf(mt_, __shfl_xor(mt_, off));
      float m_new = fmaxf(m_i[i], mt_);
      float p = __expf(s - m_new);
      float lt = p;
#pragma unroll
      for (int off = 32; off >= 1; off >>= 1) lt += __shfl_xor(lt, off);
      float alpha = __expf(m_i[i] - m_new);
      Ps[w][lane] = p;
      float acc = o_i[i] * alpha;
#pragma unroll
      for (int j = 0; j < 64; ++j) acc = fmaf(Ps[w][j], Vs[j][lane], acc);
      o_i[i] = acc;
      l_i[i] = l_i[i] * alpha + lt;
      m_i[i] = m_new;
    }
  }
#pragma unroll 1
  for (int i = 0; i < 16; ++i) {
    const int qr = q0 + w * 16 + i;
    ctx[(size_t)(b * 1024 + qr) * 1024 + hh * 64 + lane] = f2bf(o_i[i] / l_i[i]);
  }
}

// ---------------- launcher ----------------
extern "C" void kernel_launch(void* const* d_in, const int* in_sizes, int n_in,
                              void* d_out, int out_size, void* d_ws, size_t ws_size,
                              hipStream_t stream) {
  const float* embeds = (const float*)d_in[0];
  const void* amask   = d_in[1];
  const float* Wqkv = (const float*)d_in[2];
  const float* bqkv = (const float*)d_in[3];
  const float* Wo   = (const float*)d_in[4];
  const float* bo   = (const float*)d_in[5];
  const float* ln1g = (const float*)d_in[6];
  const float* ln1b = (const float*)d_in[7];
  const float* ln2g = (const float*)d_in[8];
  const float* ln2b = (const float*)d_in[9];
  const float* Wfc  = (const float*)d_in[10];
  const float* bfc  = (const float*)d_in[11];
  const float* Wpj  = (const float*)d_in[12];
  const float* bpj  = (const float*)d_in[13];
  const float* lnfg = (const float*)d_in[14];
  const float* lnfb = (const float*)d_in[15];
  float* out = (float*)d_out;

  char* ws = (char*)d_ws;
  float* h     = (float*)(ws);                            // 16 MB
  float* qkv   = (float*)(ws + (size_t)(16u << 20));      // 48 MB
  u16*   xb    = (u16*)(ws + (size_t)(64u << 20));        // 8 MB
  u16*   ffb   = (u16*)(ws + (size_t)(72u << 20));        // 32 MB
  u16*   wqT   = (u16*)(ws + (size_t)(104u << 20));       // 6 MB
  u16*   woT   = (u16*)(ws + (size_t)(110u << 20));       // 2 MB
  u16*   wfT   = (u16*)(ws + (size_t)(112u << 20));       // 8 MB
  u16*   wpT   = (u16*)(ws + (size_t)(120u << 20));       // 8 MB
  float* maskf = (float*)(ws + (size_t)(128u << 20));
  int*   pid   = (int*)(ws + (size_t)(128u << 20) + (16u << 10));

  mask_pid_kernel<<<4, 1024, 0, stream>>>(amask, maskf, pid);
  embed_kernel<<<4096, 256, 0, stream>>>(embeds, maskf, h);

  for (int l = 0; l < 4; ++l) {
    transpose_bf16<<<dim3(96, 32), dim3(32, 8), 0, stream>>>(Wqkv + (size_t)l * 1024 * 3072, wqT, 1024, 3072);
    transpose_bf16<<<dim3(32, 32), dim3(32, 8), 0, stream>>>(Wo + (size_t)l * 1024 * 1024, woT, 1024, 1024);
    transpose_bf16<<<dim3(128, 32), dim3(32, 8), 0, stream>>>(Wfc + (size_t)l * 1024 * 4096, wfT, 1024, 4096);
    transpose_bf16<<<dim3(32, 128), dim3(32, 8), 0, stream>>>(Wpj + (size_t)l * 4096 * 1024, wpT, 4096, 1024);

    ln_kernel<0><<<4096, 256, 0, stream>>>(h, ln1g + l * 1024, ln1b + l * 1024, xb, nullptr, nullptr);
    gemm_bf16<0><<<dim3(48, 64), 256, 0, stream>>>(xb, wqT, bqkv + l * 3072, qkv, nullptr, nullptr, 4096, 3072, 1024);
    rope_kernel<<<8192, 256, 0, stream>>>(qkv, pid);
    attn_kernel<<<dim3(16, 16, 4), 256, 0, stream>>>(qkv, maskf, xb);
    gemm_bf16<1><<<dim3(16, 64), 256, 0, stream>>>(xb, woT, bo + l * 1024, h, nullptr, nullptr, 4096, 1024, 1024);
    ln_kernel<0><<<4096, 256, 0, stream>>>(h, ln2g + l * 1024, ln2b + l * 1024, xb, nullptr, nullptr);
    gemm_bf16<2><<<dim3(64, 64), 256, 0, stream>>>(xb, wfT, bfc + l * 4096, nullptr, ffb, nullptr, 4096, 4096, 1024);
    gemm_bf16<3><<<dim3(16, 64), 256, 0, stream>>>(ffb, wpT, bpj + l * 1024, h, nullptr, maskf, 4096, 1024, 4096);
  }
  ln_kernel<1><<<4096, 256, 0, stream>>>(h, lnfg, lnfb, nullptr, out, maskf);
}

// Round 2
// 1671.184 us; speedup vs baseline: 3.3004x; 3.3004x over previous
//
#include <hip/hip_runtime.h>
#include <math.h>

// L=4, H=1024, NH=16, HD=64, FF=4096, B=4, S=1024
// ws layout (~129 MB): h fp32 16MB | qkv fp32 48MB | xb bf16 8MB | ffb bf16 32MB
//   (ffb region doubles as qh/kh/vh bf16 head-major between rope and attn) |
//   wqT 6MB | woT 2MB | wfT 8MB | wpT 8MB | maskf 16KB | pid 16KB

typedef unsigned short u16;
typedef unsigned int u32;
typedef __attribute__((ext_vector_type(8))) short short8;
typedef __attribute__((ext_vector_type(4))) float f32x4;
typedef __attribute__((ext_vector_type(4))) u16 u16x4;

#define NEGV (-3.402823466e38f)

__device__ __forceinline__ u16 f2bf(float f) {
  union { float f; u32 u; } v; v.f = f;
  u32 r = v.u + 0x7FFFu + ((v.u >> 16) & 1u);
  return (u16)(r >> 16);
}

__device__ __forceinline__ float gelu_tanh(float x) {
  float z = 0.7978845608028654f * (x + 0.044715f * x * x * x);
  z = fmaxf(fminf(z, 30.f), -30.f);
  float t = __expf(2.f * z);
  return 0.5f * x * (1.f + (t - 1.f) / (t + 1.f));
}

// ---------------- mask / position ids ----------------
__global__ __launch_bounds__(1024) void mask_pid_kernel(const void* __restrict__ maskp,
                                                        float* __restrict__ maskf,
                                                        int* __restrict__ pid) {
  int b = blockIdx.x, s = threadIdx.x;
  const u32* wp = (const u32*)maskp;
  bool int_mode = ((wp[0] & 0xFFFFFF00u) == 0u);
  int mv;
  if (int_mode) mv = (((const int*)maskp)[b * 1024 + s] != 0) ? 1 : 0;
  else          mv = (((const unsigned char*)maskp)[b * 1024 + s] != 0) ? 1 : 0;
  __shared__ int sc[1024];
  sc[s] = mv;
  __syncthreads();
  for (int off = 1; off < 1024; off <<= 1) {
    int add = (s >= off) ? sc[s - off] : 0;
    __syncthreads();
    sc[s] += add;
    __syncthreads();
  }
  pid[b * 1024 + s] = mv ? (sc[s] - 1) : 0;
  maskf[b * 1024 + s] = (float)mv;
}

// ---------------- h = embeds * maskf ----------------
__global__ __launch_bounds__(256) void embed_kernel(const float* __restrict__ e,
                                                    const float* __restrict__ maskf,
                                                    float* __restrict__ h) {
  int idx = blockIdx.x * 256 + threadIdx.x;
  size_t o = (size_t)idx * 4;
  int row = (int)(o >> 10);
  float mf = maskf[row];
  float4 v = *(const float4*)(e + o);
  float4 r; r.x = v.x * mf; r.y = v.y * mf; r.z = v.z * mf; r.w = v.w * mf;
  *(float4*)(h + o) = r;
}

// ---------------- transpose fp32 [K][N] -> bf16 [N][K] ----------------
__global__ __launch_bounds__(256) void transpose_bf16(const float* __restrict__ in,
                                                      u16* __restrict__ out,
                                                      int K, int N) {
  __shared__ float t[32][33];
  int tx = threadIdx.x, ty = threadIdx.y;
  int n0 = blockIdx.x * 32, k0 = blockIdx.y * 32;
#pragma unroll
  for (int j = 0; j < 4; ++j) {
    int k = ty + j * 8;
    t[k][tx] = in[(size_t)(k0 + k) * N + n0 + tx];
  }
  __syncthreads();
#pragma unroll
  for (int j = 0; j < 4; ++j) {
    int n = ty + j * 8;
    out[(size_t)(n0 + n) * K + k0 + tx] = f2bf(t[tx][n]);
  }
}

// ---------------- layernorm (H=1024) ----------------
template <int MODE>
__global__ __launch_bounds__(256) void ln_kernel(const float* __restrict__ x,
                                                 const float* __restrict__ g,
                                                 const float* __restrict__ bb,
                                                 u16* __restrict__ yb,
                                                 float* __restrict__ yf,
                                                 const float* __restrict__ maskf) {
  int row = blockIdx.x, tid = threadIdx.x;
  const float* xr = x + (size_t)row * 1024;
  float4 v = *(const float4*)(xr + tid * 4);
  float s = v.x + v.y + v.z + v.w;
  float q = v.x * v.x + v.y * v.y + v.z * v.z + v.w * v.w;
#pragma unroll
  for (int off = 32; off >= 1; off >>= 1) {
    s += __shfl_xor(s, off);
    q += __shfl_xor(q, off);
  }
  __shared__ float ps[4], pq[4];
  int w = tid >> 6, lane = tid & 63;
  if (lane == 0) { ps[w] = s; pq[w] = q; }
  __syncthreads();
  float S = ps[0] + ps[1] + ps[2] + ps[3];
  float Q = pq[0] + pq[1] + pq[2] + pq[3];
  float mean = S * (1.f / 1024.f);
  float var = fmaxf(Q * (1.f / 1024.f) - mean * mean, 0.f);
  float rstd = rsqrtf(var + 1e-5f);
  int c = tid * 4;
  float4 gv = *(const float4*)(g + c);
  float4 bv = *(const float4*)(bb + c);
  float y0 = (v.x - mean) * rstd * gv.x + bv.x;
  float y1 = (v.y - mean) * rstd * gv.y + bv.y;
  float y2 = (v.z - mean) * rstd * gv.z + bv.z;
  float y3 = (v.w - mean) * rstd * gv.w + bv.w;
  if (MODE == 0) {
    u16x4 o; o.x = f2bf(y0); o.y = f2bf(y1); o.z = f2bf(y2); o.w = f2bf(y3);
    *(u16x4*)(yb + (size_t)row * 1024 + c) = o;
  } else {
    float mf = maskf[row];
    float4 o; o.x = y0 * mf; o.y = y1 * mf; o.z = y2 * mf; o.w = y3 * mf;
    *(float4*)(yf + (size_t)row * 1024 + c) = o;
  }
}

// ---------------- bf16 MFMA GEMM: C[M,N] = A[M,K] @ Bt[N,K]^T + bias ----------------
template <int EPI>
__global__ __launch_bounds__(256) void gemm_bf16(const u16* __restrict__ A,
                                                 const u16* __restrict__ Bt,
                                                 const float* __restrict__ bias,
                                                 float* __restrict__ Of,
                                                 u16* __restrict__ Ob,
                                                 const float* __restrict__ maskf,
                                                 int M, int N, int K) {
  __shared__ __align__(16) u16 As[64][40];
  __shared__ __align__(16) u16 Bs[64][40];
  const int tid = threadIdx.x;
  const int lane = tid & 63, w = tid >> 6;
  const int wm = w >> 1, wn = w & 1;
  const int m0 = blockIdx.y * 64, n0 = blockIdx.x * 64;
  const int lm = lane & 15, lq = lane >> 4;

  f32x4 acc[2][2] = {};
  const int r = tid >> 2;
  const int cg = (tid & 3) * 8;
  const u16* Ap = A + (size_t)(m0 + r) * K + cg;
  const u16* Bp = Bt + (size_t)(n0 + r) * K + cg;

  for (int k0 = 0; k0 < K; k0 += 32) {
    uint4 av = *(const uint4*)(Ap + k0);
    uint4 bv = *(const uint4*)(Bp + k0);
    *(uint4*)(&As[r][cg]) = av;
    *(uint4*)(&Bs[r][cg]) = bv;
    __syncthreads();
    short8 af[2], bf[2];
    af[0] = *(const short8*)(&As[wm * 32 + lm][lq * 8]);
    af[1] = *(const short8*)(&As[wm * 32 + 16 + lm][lq * 8]);
    bf[0] = *(const short8*)(&Bs[wn * 32 + lm][lq * 8]);
    bf[1] = *(const short8*)(&Bs[wn * 32 + 16 + lm][lq * 8]);
#pragma unroll
    for (int mt = 0; mt < 2; ++mt)
#pragma unroll
      for (int nt = 0; nt < 2; ++nt)
        acc[mt][nt] = __builtin_amdgcn_mfma_f32_16x16x32_bf16(af[mt], bf[nt], acc[mt][nt], 0, 0, 0);
    __syncthreads();
  }

#pragma unroll
  for (int mt = 0; mt < 2; ++mt) {
#pragma unroll
    for (int nt = 0; nt < 2; ++nt) {
      int col = n0 + wn * 32 + nt * 16 + lm;
      float bvv = bias[col];
#pragma unroll
      for (int rr = 0; rr < 4; ++rr) {
        int row = m0 + wm * 32 + mt * 16 + lq * 4 + rr;
        size_t idx = (size_t)row * N + col;
        float v = acc[mt][nt][rr] + bvv;
        if (EPI == 0) {
          Of[idx] = v;
        } else if (EPI == 1) {
          Of[idx] += v;
        } else if (EPI == 2) {
          Ob[idx] = f2bf(gelu_tanh(v));
        } else {
          Of[idx] = (Of[idx] + v) * maskf[row];
        }
      }
    }
  }
}

// ---------------- RoPE: qkv fp32 [4096][3072] -> bf16 head-major q,k,v [B*NH*S][64] --------
__global__ __launch_bounds__(256) void rope_kernel(const float* __restrict__ qkv,
                                                   const int* __restrict__ pid,
                                                   u16* __restrict__ qh,
                                                   u16* __restrict__ kh,
                                                   u16* __restrict__ vh) {
  int idx = blockIdx.x * 256 + threadIdx.x;  // 4096*16*32
  int i = idx & 31;
  int hh = (idx >> 5) & 15;
  int row = idx >> 9;
  int b = row >> 10, s = row & 1023;
  float p = (float)pid[row];
  float inv = __expf(-(float)(2 * i) * (9.210340371976184f / 64.f));
  float th = p * inv;
  float c = cosf(th), sn = sinf(th);
  size_t base = (size_t)row * 3072 + hh * 64 + 2 * i;
  float q0 = qkv[base], q1 = qkv[base + 1];
  float k0 = qkv[base + 1024], k1 = qkv[base + 1025];
  float v0 = qkv[base + 2048], v1 = qkv[base + 2049];
  float qr0 = (q0 * c - q1 * sn) * 0.125f;
  float qr1 = (q1 * c + q0 * sn) * 0.125f;
  float kr0 = k0 * c - k1 * sn;
  float kr1 = k1 * c + k0 * sn;
  size_t hbase = ((size_t)(b * 16 + hh) * 1024 + s) * 64 + 2 * i;
  *(u32*)(qh + hbase) = (u32)f2bf(qr0) | ((u32)f2bf(qr1) << 16);
  *(u32*)(kh + hbase) = (u32)f2bf(kr0) | ((u32)f2bf(kr1) << 16);
  *(u32*)(vh + hbase) = (u32)f2bf(v0) | ((u32)f2bf(v1) << 16);
}

// ---------------- MFMA flash attention ----------------
// block = 4 waves; wave w owns q-rows q0+w*16 .. +15; k-tiles of 64.
__global__ __launch_bounds__(256) void attn_mfma(const u16* __restrict__ qh,
                                                 const u16* __restrict__ kh,
                                                 const u16* __restrict__ vh,
                                                 const float* __restrict__ maskf,
                                                 u16* __restrict__ ctx) {
  const int b = blockIdx.z, h = blockIdx.y, qt = blockIdx.x;
  const int tid = threadIdx.x, lane = tid & 63, w = tid >> 6;
  const int ln = lane & 15, kg = lane >> 4;
  const int q0 = qt * 64;
  const size_t hb = (size_t)(b * 16 + h) * 1024 * 64;

  __shared__ __align__(16) u16 Ks[64][72];
  __shared__ __align__(16) u16 VsT[64][72];  // [d][key]
  __shared__ __align__(16) u16 Ps[64][72];   // [q local][key]
  __shared__ float Ms[64];

  // Q A-fragments straight from global (constant across k-tiles)
  const int qrow = q0 + w * 16 + ln;
  short8 qa0 = *(const short8*)(qh + hb + (size_t)qrow * 64 + kg * 8);
  short8 qa1 = *(const short8*)(qh + hb + (size_t)qrow * 64 + 32 + kg * 8);

  f32x4 Oc[4] = {};        // O[q][d] chunks over d; reg r -> q row kg*4+r
  float m_i[4], l_i[4];
#pragma unroll
  for (int r = 0; r < 4; ++r) { m_i[r] = NEGV; l_i[r] = 0.f; }

  const int ntiles = qt + 1;
  for (int t = 0; t < ntiles; ++t) {
    __syncthreads();
    // stage K row-major
    {
      int row = tid >> 2, c8 = (tid & 3) * 8;
      const u16* kp2 = kh + hb + (size_t)(t * 64 + row) * 64;
      *(uint4*)(&Ks[row][c8]) = *(const uint4*)(kp2 + c8);
      *(uint4*)(&Ks[row][c8 + 32]) = *(const uint4*)(kp2 + c8 + 32);
    }
    // stage V transposed [d][key] via packed u32 writes
    {
      int kp = tid >> 3, dg = tid & 7;
      const u16* vp0 = vh + hb + (size_t)(t * 64 + 2 * kp) * 64 + dg * 8;
      uint4 r0 = *(const uint4*)vp0;
      uint4 r1 = *(const uint4*)(vp0 + 64);
      u32 a0[4] = {r0.x, r0.y, r0.z, r0.w};
      u32 a1[4] = {r1.x, r1.y, r1.z, r1.w};
#pragma unroll
      for (int j = 0; j < 8; ++j) {
        u32 lo = (a0[j >> 1] >> (16 * (j & 1))) & 0xffffu;
        u32 hi = (a1[j >> 1] >> (16 * (j & 1))) & 0xffffu;
        *(u32*)(&VsT[dg * 8 + j][2 * kp]) = lo | (hi << 16);
      }
    }
    if (tid < 64) Ms[tid] = maskf[b * 1024 + t * 64 + tid];
    __syncthreads();

    // S = Q @ K^T  (4 chunks of 16 keys)
    f32x4 Sc[4];
#pragma unroll
    for (int c = 0; c < 4; ++c) {
      short8 kb0 = *(const short8*)(&Ks[c * 16 + ln][kg * 8]);
      short8 kb1 = *(const short8*)(&Ks[c * 16 + ln][32 + kg * 8]);
      f32x4 z = {};
      z = __builtin_amdgcn_mfma_f32_16x16x32_bf16(qa0, kb0, z, 0, 0, 0);
      Sc[c] = __builtin_amdgcn_mfma_f32_16x16x32_bf16(qa1, kb1, Sc[c] = z, 0, 0, 0);
    }
    float mk[4];
#pragma unroll
    for (int c = 0; c < 4; ++c) mk[c] = Ms[c * 16 + ln];

    // online softmax per q-row (row = kg*4 + r, key col = c*16 + ln)
#pragma unroll
    for (int r = 0; r < 4; ++r) {
      int qg = q0 + w * 16 + kg * 4 + r;
      float vmax = NEGV;
#pragma unroll
      for (int c = 0; c < 4; ++c) {
        int key = t * 64 + c * 16 + ln;
        bool valid = (key <= qg) && (mk[c] != 0.f);
        float sv = valid ? Sc[c][r] : NEGV;
        Sc[c][r] = sv;
        vmax = fmaxf(vmax, sv);
      }
#pragma unroll
      for (int off = 1; off <= 8; off <<= 1) vmax = fmaxf(vmax, __shfl_xor(vmax, off));
      float mnew = fmaxf(m_i[r], vmax);
      float alpha = __expf(m_i[r] - mnew);
      m_i[r] = mnew;
      float ls = 0.f;
#pragma unroll
      for (int c = 0; c < 4; ++c) {
        float p = __expf(Sc[c][r] - mnew);
        Sc[c][r] = p;
        ls += p;
      }
#pragma unroll
      for (int off = 1; off <= 8; off <<= 1) ls += __shfl_xor(ls, off);
      l_i[r] = l_i[r] * alpha + ls;
#pragma unroll
      for (int c = 0; c < 4; ++c) Oc[c][r] *= alpha;
#pragma unroll
      for (int c = 0; c < 4; ++c) Ps[w * 16 + kg * 4 + r][c * 16 + ln] = f2bf(Sc[c][r]);
    }
    __syncthreads();

    // O += P @ V
    short8 pa0 = *(const short8*)(&Ps[w * 16 + ln][kg * 8]);
    short8 pa1 = *(const short8*)(&Ps[w * 16 + ln][32 + kg * 8]);
#pragma unroll
    for (int c = 0; c < 4; ++c) {
      short8 vb0 = *(const short8*)(&VsT[c * 16 + ln][kg * 8]);
      short8 vb1 = *(const short8*)(&VsT[c * 16 + ln][32 + kg * 8]);
      Oc[c] = __builtin_amdgcn_mfma_f32_16x16x32_bf16(pa0, vb0, Oc[c], 0, 0, 0);
      Oc[c] = __builtin_amdgcn_mfma_f32_16x16x32_bf16(pa1, vb1, Oc[c], 0, 0, 0);
    }
  }

  // epilogue: normalize and store bf16 ctx [B*S][H]
#pragma unroll
  for (int r = 0; r < 4; ++r) {
    float rl = 1.f / l_i[r];
    int row = q0 + w * 16 + kg * 4 + r;
#pragma unroll
    for (int c = 0; c < 4; ++c) {
      ctx[(size_t)(b * 1024 + row) * 1024 + h * 64 + c * 16 + ln] = f2bf(Oc[c][r] * rl);
    }
  }
}

// ---------------- launcher ----------------
extern "C" void kernel_launch(void* const* d_in, const int* in_sizes, int n_in,
                              void* d_out, int out_size, void* d_ws, size_t ws_size,
                              hipStream_t stream) {
  const float* embeds = (const float*)d_in[0];
  const void* amask   = d_in[1];
  const float* Wqkv = (const float*)d_in[2];
  const float* bqkv = (const float*)d_in[3];
  const float* Wo   = (const float*)d_in[4];
  const float* bo   = (const float*)d_in[5];
  const float* ln1g = (const float*)d_in[6];
  const float* ln1b = (const float*)d_in[7];
  const float* ln2g = (const float*)d_in[8];
  const float* ln2b = (const float*)d_in[9];
  const float* Wfc  = (const float*)d_in[10];
  const float* bfc  = (const float*)d_in[11];
  const float* Wpj  = (const float*)d_in[12];
  const float* bpj  = (const float*)d_in[13];
  const float* lnfg = (const float*)d_in[14];
  const float* lnfb = (const float*)d_in[15];
  float* out = (float*)d_out;

  char* ws = (char*)d_ws;
  float* h     = (float*)(ws);                            // 16 MB
  float* qkv   = (float*)(ws + (size_t)(16u << 20));      // 48 MB
  u16*   xb    = (u16*)(ws + (size_t)(64u << 20));        // 8 MB
  u16*   ffb   = (u16*)(ws + (size_t)(72u << 20));        // 32 MB (also qh/kh/vh)
  u16*   qhp   = (u16*)(ws + (size_t)(72u << 20));        // 8 MB
  u16*   khp   = (u16*)(ws + (size_t)(80u << 20));        // 8 MB
  u16*   vhp   = (u16*)(ws + (size_t)(88u << 20));        // 8 MB
  u16*   wqT   = (u16*)(ws + (size_t)(104u << 20));       // 6 MB
  u16*   woT   = (u16*)(ws + (size_t)(110u << 20));       // 2 MB
  u16*   wfT   = (u16*)(ws + (size_t)(112u << 20));       // 8 MB
  u16*   wpT   = (u16*)(ws + (size_t)(120u << 20));       // 8 MB
  float* maskf = (float*)(ws + (size_t)(128u << 20));
  int*   pid   = (int*)(ws + (size_t)(128u << 20) + (16u << 10));

  mask_pid_kernel<<<4, 1024, 0, stream>>>(amask, maskf, pid);
  embed_kernel<<<4096, 256, 0, stream>>>(embeds, maskf, h);

  for (int l = 0; l < 4; ++l) {
    transpose_bf16<<<dim3(96, 32), dim3(32, 8), 0, stream>>>(Wqkv + (size_t)l * 1024 * 3072, wqT, 1024, 3072);
    transpose_bf16<<<dim3(32, 32), dim3(32, 8), 0, stream>>>(Wo + (size_t)l * 1024 * 1024, woT, 1024, 1024);
    transpose_bf16<<<dim3(128, 32), dim3(32, 8), 0, stream>>>(Wfc + (size_t)l * 1024 * 4096, wfT, 1024, 4096);
    transpose_bf16<<<dim3(32, 128), dim3(32, 8), 0, stream>>>(Wpj + (size_t)l * 4096 * 1024, wpT, 4096, 1024);

    ln_kernel<0><<<4096, 256, 0, stream>>>(h, ln1g + l * 1024, ln1b + l * 1024, xb, nullptr, nullptr);
    gemm_bf16<0><<<dim3(48, 64), 256, 0, stream>>>(xb, wqT, bqkv + l * 3072, qkv, nullptr, nullptr, 4096, 3072, 1024);
    rope_kernel<<<8192, 256, 0, stream>>>(qkv, pid, qhp, khp, vhp);
    attn_mfma<<<dim3(16, 16, 4), 256, 0, stream>>>(qhp, khp, vhp, maskf, xb);
    gemm_bf16<1><<<dim3(16, 64), 256, 0, stream>>>(xb, woT, bo + l * 1024, h, nullptr, nullptr, 4096, 1024, 1024);
    ln_kernel<0><<<4096, 256, 0, stream>>>(h, ln2g + l * 1024, ln2b + l * 1024, xb, nullptr, nullptr);
    gemm_bf16<2><<<dim3(64, 64), 256, 0, stream>>>(xb, wfT, bfc + l * 4096, nullptr, ffb, nullptr, 4096, 4096, 1024);
    gemm_bf16<3><<<dim3(16, 64), 256, 0, stream>>>(ffb, wpT, bpj + l * 1024, h, nullptr, maskf, 4096, 1024, 4096);
  }
  ln_kernel<1><<<4096, 256, 0, stream>>>(h, lnfg, lnfb, nullptr, out, maskf);
}

// Round 3
// 1598.346 us; speedup vs baseline: 3.4508x; 1.0456x over previous
//
#include <hip/hip_runtime.h>
#include <math.h>

// L=4, H=1024, NH=16, HD=64, FF=4096, B=4, S=1024
// ws layout (~129 MB): h fp32 16MB | qkv fp32 48MB | xb bf16 8MB | ffb bf16 32MB
//   (ffb region doubles as qh/kh/vh bf16 head-major between rope and attn) |
//   wqT 6MB | woT 2MB | wfT 8MB | wpT 8MB | maskf 16KB | pid 16KB

typedef unsigned short u16;
typedef unsigned int u32;
typedef __attribute__((ext_vector_type(8))) short short8;
typedef __attribute__((ext_vector_type(4))) float f32x4;
typedef __attribute__((ext_vector_type(4))) u16 u16x4;

#define NEGV (-3.402823466e38f)

__device__ __forceinline__ u16 f2bf(float f) {
  union { float f; u32 u; } v; v.f = f;
  u32 r = v.u + 0x7FFFu + ((v.u >> 16) & 1u);
  return (u16)(r >> 16);
}

__device__ __forceinline__ float gelu_tanh(float x) {
  float z = 0.7978845608028654f * (x + 0.044715f * x * x * x);
  z = fmaxf(fminf(z, 30.f), -30.f);
  float t = __expf(2.f * z);
  return 0.5f * x * (1.f + (t - 1.f) / (t + 1.f));
}

// async 16B global -> LDS (DMA, no VGPR round-trip). LDS dest must be
// wave-uniform base + lane*16 (linear lane order) — no padding allowed.
__device__ __forceinline__ void gld_lds16(const u16* g, u16* l) {
  __builtin_amdgcn_global_load_lds((const __attribute__((address_space(1))) u32*)g,
                                   (__attribute__((address_space(3))) u32*)l, 16, 0, 0);
}

// ---------------- mask / position ids ----------------
__global__ __launch_bounds__(1024) void mask_pid_kernel(const void* __restrict__ maskp,
                                                        float* __restrict__ maskf,
                                                        int* __restrict__ pid) {
  int b = blockIdx.x, s = threadIdx.x;
  const u32* wp = (const u32*)maskp;
  bool int_mode = ((wp[0] & 0xFFFFFF00u) == 0u);
  int mv;
  if (int_mode) mv = (((const int*)maskp)[b * 1024 + s] != 0) ? 1 : 0;
  else          mv = (((const unsigned char*)maskp)[b * 1024 + s] != 0) ? 1 : 0;
  __shared__ int sc[1024];
  sc[s] = mv;
  __syncthreads();
  for (int off = 1; off < 1024; off <<= 1) {
    int add = (s >= off) ? sc[s - off] : 0;
    __syncthreads();
    sc[s] += add;
    __syncthreads();
  }
  pid[b * 1024 + s] = mv ? (sc[s] - 1) : 0;
  maskf[b * 1024 + s] = (float)mv;
}

// ---------------- h = embeds * maskf ----------------
__global__ __launch_bounds__(256) void embed_kernel(const float* __restrict__ e,
                                                    const float* __restrict__ maskf,
                                                    float* __restrict__ h) {
  int idx = blockIdx.x * 256 + threadIdx.x;
  size_t o = (size_t)idx * 4;
  int row = (int)(o >> 10);
  float mf = maskf[row];
  float4 v = *(const float4*)(e + o);
  float4 r; r.x = v.x * mf; r.y = v.y * mf; r.z = v.z * mf; r.w = v.w * mf;
  *(float4*)(h + o) = r;
}

// ---------------- transpose fp32 [K][N] -> bf16 [N][K] ----------------
__global__ __launch_bounds__(256) void transpose_bf16(const float* __restrict__ in,
                                                      u16* __restrict__ out,
                                                      int K, int N) {
  __shared__ float t[32][33];
  int tx = threadIdx.x, ty = threadIdx.y;
  int n0 = blockIdx.x * 32, k0 = blockIdx.y * 32;
#pragma unroll
  for (int j = 0; j < 4; ++j) {
    int k = ty + j * 8;
    t[k][tx] = in[(size_t)(k0 + k) * N + n0 + tx];
  }
  __syncthreads();
#pragma unroll
  for (int j = 0; j < 4; ++j) {
    int n = ty + j * 8;
    out[(size_t)(n0 + n) * K + k0 + tx] = f2bf(t[tx][n]);
  }
}

// ---------------- layernorm (H=1024) ----------------
template <int MODE>
__global__ __launch_bounds__(256) void ln_kernel(const float* __restrict__ x,
                                                 const float* __restrict__ g,
                                                 const float* __restrict__ bb,
                                                 u16* __restrict__ yb,
                                                 float* __restrict__ yf,
                                                 const float* __restrict__ maskf) {
  int row = blockIdx.x, tid = threadIdx.x;
  const float* xr = x + (size_t)row * 1024;
  float4 v = *(const float4*)(xr + tid * 4);
  float s = v.x + v.y + v.z + v.w;
  float q = v.x * v.x + v.y * v.y + v.z * v.z + v.w * v.w;
#pragma unroll
  for (int off = 32; off >= 1; off >>= 1) {
    s += __shfl_xor(s, off);
    q += __shfl_xor(q, off);
  }
  __shared__ float ps[4], pq[4];
  int w = tid >> 6, lane = tid & 63;
  if (lane == 0) { ps[w] = s; pq[w] = q; }
  __syncthreads();
  float S = ps[0] + ps[1] + ps[2] + ps[3];
  float Q = pq[0] + pq[1] + pq[2] + pq[3];
  float mean = S * (1.f / 1024.f);
  float var = fmaxf(Q * (1.f / 1024.f) - mean * mean, 0.f);
  float rstd = rsqrtf(var + 1e-5f);
  int c = tid * 4;
  float4 gv = *(const float4*)(g + c);
  float4 bv = *(const float4*)(bb + c);
  float y0 = (v.x - mean) * rstd * gv.x + bv.x;
  float y1 = (v.y - mean) * rstd * gv.y + bv.y;
  float y2 = (v.z - mean) * rstd * gv.z + bv.z;
  float y3 = (v.w - mean) * rstd * gv.w + bv.w;
  if (MODE == 0) {
    u16x4 o; o.x = f2bf(y0); o.y = f2bf(y1); o.z = f2bf(y2); o.w = f2bf(y3);
    *(u16x4*)(yb + (size_t)row * 1024 + c) = o;
  } else {
    float mf = maskf[row];
    float4 o; o.x = y0 * mf; o.y = y1 * mf; o.z = y2 * mf; o.w = y3 * mf;
    *(float4*)(yf + (size_t)row * 1024 + c) = o;
  }
}

// ---------------- 128x128 bf16 MFMA GEMM (m97 structure) ----------------
// C[M,N] = A[M,K] @ Bt[N,K]^T + bias, K % 32 == 0, M,N % 128 == 0.
// 4 waves, each 64x64 (4x4 MFMA 16x16x32). LDS staged via global_load_lds x16.
// EPI 0: Of = v   1: Of += v   2: Ob = bf16(gelu(v))   3: Of = (Of+v)*maskf[row]
template <int EPI>
__global__ __launch_bounds__(256) void gemm128(const u16* __restrict__ A,
                                               const u16* __restrict__ Bt,
                                               const float* __restrict__ bias,
                                               float* __restrict__ Of,
                                               u16* __restrict__ Ob,
                                               const float* __restrict__ maskf,
                                               int M, int N, int K) {
  __shared__ __align__(16) u16 As[128 * 32];
  __shared__ __align__(16) u16 Bs[128 * 32];
  const int tid = threadIdx.x;
  const int lane = tid & 63, w = tid >> 6;
  const int wm = w >> 1, wn = w & 1;
  const int m0 = blockIdx.y * 128, n0 = blockIdx.x * 128;
  const int ln = lane & 15, kg = lane >> 4;

  f32x4 acc[4][4] = {};

  // staging: 512 16B segments per tile; seg s -> row s>>2, colgroup (s&3)*8.
  const int r0 = tid >> 2, g0 = (tid & 3) * 8;
  const u16* Ap0 = A + (size_t)(m0 + r0) * K + g0;
  const u16* Ap1 = A + (size_t)(m0 + 64 + r0) * K + g0;
  const u16* Bp0 = Bt + (size_t)(n0 + r0) * K + g0;
  const u16* Bp1 = Bt + (size_t)(n0 + 64 + r0) * K + g0;
  u16* AsD0 = As + tid * 8;           // byte offset tid*16
  u16* AsD1 = As + (tid + 256) * 8;
  u16* BsD0 = Bs + tid * 8;
  u16* BsD1 = Bs + (tid + 256) * 8;

  for (int k0 = 0; k0 < K; k0 += 32) {
    __syncthreads();  // previous iter's frag reads done before overwrite
    gld_lds16(Ap0 + k0, AsD0);
    gld_lds16(Ap1 + k0, AsD1);
    gld_lds16(Bp0 + k0, BsD0);
    gld_lds16(Bp1 + k0, BsD1);
    __syncthreads();  // compiler drains vmcnt(0) before barrier

    short8 af[4], bfr[4];
#pragma unroll
    for (int mt = 0; mt < 4; ++mt)
      af[mt] = *(const short8*)(As + (wm * 64 + mt * 16 + ln) * 32 + kg * 8);
#pragma unroll
    for (int nt = 0; nt < 4; ++nt)
      bfr[nt] = *(const short8*)(Bs + (wn * 64 + nt * 16 + ln) * 32 + kg * 8);
#pragma unroll
    for (int mt = 0; mt < 4; ++mt)
#pragma unroll
      for (int nt = 0; nt < 4; ++nt)
        acc[mt][nt] = __builtin_amdgcn_mfma_f32_16x16x32_bf16(af[mt], bfr[nt], acc[mt][nt], 0, 0, 0);
  }

#pragma unroll
  for (int mt = 0; mt < 4; ++mt) {
#pragma unroll
    for (int nt = 0; nt < 4; ++nt) {
      int col = n0 + wn * 64 + nt * 16 + ln;
      float bvv = bias[col];
#pragma unroll
      for (int rr = 0; rr < 4; ++rr) {
        int row = m0 + wm * 64 + mt * 16 + kg * 4 + rr;
        size_t idx = (size_t)row * N + col;
        float v = acc[mt][nt][rr] + bvv;
        if (EPI == 0) {
          Of[idx] = v;
        } else if (EPI == 1) {
          Of[idx] += v;
        } else if (EPI == 2) {
          Ob[idx] = f2bf(gelu_tanh(v));
        } else {
          Of[idx] = (Of[idx] + v) * maskf[row];
        }
      }
    }
  }
}

// ---------------- RoPE: qkv fp32 [4096][3072] -> bf16 head-major q,k,v [B*NH*S][64] --------
__global__ __launch_bounds__(256) void rope_kernel(const float* __restrict__ qkv,
                                                   const int* __restrict__ pid,
                                                   u16* __restrict__ qh,
                                                   u16* __restrict__ kh,
                                                   u16* __restrict__ vh) {
  int idx = blockIdx.x * 256 + threadIdx.x;  // 4096*16*32
  int i = idx & 31;
  int hh = (idx >> 5) & 15;
  int row = idx >> 9;
  int b = row >> 10, s = row & 1023;
  float p = (float)pid[row];
  float inv = __expf(-(float)(2 * i) * (9.210340371976184f / 64.f));
  float th = p * inv;
  float c = cosf(th), sn = sinf(th);
  size_t base = (size_t)row * 3072 + hh * 64 + 2 * i;
  float q0 = qkv[base], q1 = qkv[base + 1];
  float k0 = qkv[base + 1024], k1 = qkv[base + 1025];
  float v0 = qkv[base + 2048], v1 = qkv[base + 2049];
  float qr0 = (q0 * c - q1 * sn) * 0.125f;
  float qr1 = (q1 * c + q0 * sn) * 0.125f;
  float kr0 = k0 * c - k1 * sn;
  float kr1 = k1 * c + k0 * sn;
  size_t hbase = ((size_t)(b * 16 + hh) * 1024 + s) * 64 + 2 * i;
  *(u32*)(qh + hbase) = (u32)f2bf(qr0) | ((u32)f2bf(qr1) << 16);
  *(u32*)(kh + hbase) = (u32)f2bf(kr0) | ((u32)f2bf(kr1) << 16);
  *(u32*)(vh + hbase) = (u32)f2bf(v0) | ((u32)f2bf(v1) << 16);
}

// ---------------- MFMA flash attention ----------------
__global__ __launch_bounds__(256) void attn_mfma(const u16* __restrict__ qh,
                                                 const u16* __restrict__ kh,
                                                 const u16* __restrict__ vh,
                                                 const float* __restrict__ maskf,
                                                 u16* __restrict__ ctx) {
  const int b = blockIdx.z, h = blockIdx.y, qt = blockIdx.x;
  const int tid = threadIdx.x, lane = tid & 63, w = tid >> 6;
  const int ln = lane & 15, kg = lane >> 4;
  const int q0 = qt * 64;
  const size_t hb = (size_t)(b * 16 + h) * 1024 * 64;

  __shared__ __align__(16) u16 Ks[64][72];
  __shared__ __align__(16) u16 VsT[64][72];  // [d][key]
  __shared__ __align__(16) u16 Ps[64][72];   // [q local][key]
  __shared__ float Ms[64];

  const int qrow = q0 + w * 16 + ln;
  short8 qa0 = *(const short8*)(qh + hb + (size_t)qrow * 64 + kg * 8);
  short8 qa1 = *(const short8*)(qh + hb + (size_t)qrow * 64 + 32 + kg * 8);

  f32x4 Oc[4] = {};
  float m_i[4], l_i[4];
#pragma unroll
  for (int r = 0; r < 4; ++r) { m_i[r] = NEGV; l_i[r] = 0.f; }

  const int ntiles = qt + 1;
  for (int t = 0; t < ntiles; ++t) {
    __syncthreads();
    {
      int row = tid >> 2, c8 = (tid & 3) * 8;
      const u16* kp2 = kh + hb + (size_t)(t * 64 + row) * 64;
      *(uint4*)(&Ks[row][c8]) = *(const uint4*)(kp2 + c8);
      *(uint4*)(&Ks[row][c8 + 32]) = *(const uint4*)(kp2 + c8 + 32);
    }
    {
      int kp = tid >> 3, dg = tid & 7;
      const u16* vp0 = vh + hb + (size_t)(t * 64 + 2 * kp) * 64 + dg * 8;
      uint4 r0 = *(const uint4*)vp0;
      uint4 r1 = *(const uint4*)(vp0 + 64);
      u32 a0[4] = {r0.x, r0.y, r0.z, r0.w};
      u32 a1[4] = {r1.x, r1.y, r1.z, r1.w};
#pragma unroll
      for (int j = 0; j < 8; ++j) {
        u32 lo = (a0[j >> 1] >> (16 * (j & 1))) & 0xffffu;
        u32 hi = (a1[j >> 1] >> (16 * (j & 1))) & 0xffffu;
        *(u32*)(&VsT[dg * 8 + j][2 * kp]) = lo | (hi << 16);
      }
    }
    if (tid < 64) Ms[tid] = maskf[b * 1024 + t * 64 + tid];
    __syncthreads();

    f32x4 Sc[4];
#pragma unroll
    for (int c = 0; c < 4; ++c) {
      short8 kb0 = *(const short8*)(&Ks[c * 16 + ln][kg * 8]);
      short8 kb1 = *(const short8*)(&Ks[c * 16 + ln][32 + kg * 8]);
      f32x4 z = {};
      z = __builtin_amdgcn_mfma_f32_16x16x32_bf16(qa0, kb0, z, 0, 0, 0);
      Sc[c] = __builtin_amdgcn_mfma_f32_16x16x32_bf16(qa1, kb1, z, 0, 0, 0);
    }
    float mk[4];
#pragma unroll
    for (int c = 0; c < 4; ++c) mk[c] = Ms[c * 16 + ln];

#pragma unroll
    for (int r = 0; r < 4; ++r) {
      int qg = q0 + w * 16 + kg * 4 + r;
      float vmax = NEGV;
#pragma unroll
      for (int c = 0; c < 4; ++c) {
        int key = t * 64 + c * 16 + ln;
        bool valid = (key <= qg) && (mk[c] != 0.f);
        float sv = valid ? Sc[c][r] : NEGV;
        Sc[c][r] = sv;
        vmax = fmaxf(vmax, sv);
      }
#pragma unroll
      for (int off = 1; off <= 8; off <<= 1) vmax = fmaxf(vmax, __shfl_xor(vmax, off));
      float mnew = fmaxf(m_i[r], vmax);
      float alpha = __expf(m_i[r] - mnew);
      m_i[r] = mnew;
      float ls = 0.f;
#pragma unroll
      for (int c = 0; c < 4; ++c) {
        float p = __expf(Sc[c][r] - mnew);
        Sc[c][r] = p;
        ls += p;
      }
#pragma unroll
      for (int off = 1; off <= 8; off <<= 1) ls += __shfl_xor(ls, off);
      l_i[r] = l_i[r] * alpha + ls;
#pragma unroll
      for (int c = 0; c < 4; ++c) Oc[c][r] *= alpha;
#pragma unroll
      for (int c = 0; c < 4; ++c) Ps[w * 16 + kg * 4 + r][c * 16 + ln] = f2bf(Sc[c][r]);
    }
    __syncthreads();

    short8 pa0 = *(const short8*)(&Ps[w * 16 + ln][kg * 8]);
    short8 pa1 = *(const short8*)(&Ps[w * 16 + ln][32 + kg * 8]);
#pragma unroll
    for (int c = 0; c < 4; ++c) {
      short8 vb0 = *(const short8*)(&VsT[c * 16 + ln][kg * 8]);
      short8 vb1 = *(const short8*)(&VsT[c * 16 + ln][32 + kg * 8]);
      Oc[c] = __builtin_amdgcn_mfma_f32_16x16x32_bf16(pa0, vb0, Oc[c], 0, 0, 0);
      Oc[c] = __builtin_amdgcn_mfma_f32_16x16x32_bf16(pa1, vb1, Oc[c], 0, 0, 0);
    }
  }

#pragma unroll
  for (int r = 0; r < 4; ++r) {
    float rl = 1.f / l_i[r];
    int row = q0 + w * 16 + kg * 4 + r;
#pragma unroll
    for (int c = 0; c < 4; ++c) {
      ctx[(size_t)(b * 1024 + row) * 1024 + h * 64 + c * 16 + ln] = f2bf(Oc[c][r] * rl);
    }
  }
}

// ---------------- launcher ----------------
extern "C" void kernel_launch(void* const* d_in, const int* in_sizes, int n_in,
                              void* d_out, int out_size, void* d_ws, size_t ws_size,
                              hipStream_t stream) {
  const float* embeds = (const float*)d_in[0];
  const void* amask   = d_in[1];
  const float* Wqkv = (const float*)d_in[2];
  const float* bqkv = (const float*)d_in[3];
  const float* Wo   = (const float*)d_in[4];
  const float* bo   = (const float*)d_in[5];
  const float* ln1g = (const float*)d_in[6];
  const float* ln1b = (const float*)d_in[7];
  const float* ln2g = (const float*)d_in[8];
  const float* ln2b = (const float*)d_in[9];
  const float* Wfc  = (const float*)d_in[10];
  const float* bfc  = (const float*)d_in[11];
  const float* Wpj  = (const float*)d_in[12];
  const float* bpj  = (const float*)d_in[13];
  const float* lnfg = (const float*)d_in[14];
  const float* lnfb = (const float*)d_in[15];
  float* out = (float*)d_out;

  char* ws = (char*)d_ws;
  float* h     = (float*)(ws);                            // 16 MB
  float* qkv   = (float*)(ws + (size_t)(16u << 20));      // 48 MB
  u16*   xb    = (u16*)(ws + (size_t)(64u << 20));        // 8 MB
  u16*   ffb   = (u16*)(ws + (size_t)(72u << 20));        // 32 MB (also qh/kh/vh)
  u16*   qhp   = (u16*)(ws + (size_t)(72u << 20));        // 8 MB
  u16*   khp   = (u16*)(ws + (size_t)(80u << 20));        // 8 MB
  u16*   vhp   = (u16*)(ws + (size_t)(88u << 20));        // 8 MB
  u16*   wqT   = (u16*)(ws + (size_t)(104u << 20));       // 6 MB
  u16*   woT   = (u16*)(ws + (size_t)(110u << 20));       // 2 MB
  u16*   wfT   = (u16*)(ws + (size_t)(112u << 20));       // 8 MB
  u16*   wpT   = (u16*)(ws + (size_t)(120u << 20));       // 8 MB
  float* maskf = (float*)(ws + (size_t)(128u << 20));
  int*   pid   = (int*)(ws + (size_t)(128u << 20) + (16u << 10));

  mask_pid_kernel<<<4, 1024, 0, stream>>>(amask, maskf, pid);
  embed_kernel<<<4096, 256, 0, stream>>>(embeds, maskf, h);

  for (int l = 0; l < 4; ++l) {
    transpose_bf16<<<dim3(96, 32), dim3(32, 8), 0, stream>>>(Wqkv + (size_t)l * 1024 * 3072, wqT, 1024, 3072);
    transpose_bf16<<<dim3(32, 32), dim3(32, 8), 0, stream>>>(Wo + (size_t)l * 1024 * 1024, woT, 1024, 1024);
    transpose_bf16<<<dim3(128, 32), dim3(32, 8), 0, stream>>>(Wfc + (size_t)l * 1024 * 4096, wfT, 1024, 4096);
    transpose_bf16<<<dim3(32, 128), dim3(32, 8), 0, stream>>>(Wpj + (size_t)l * 4096 * 1024, wpT, 4096, 1024);

    ln_kernel<0><<<4096, 256, 0, stream>>>(h, ln1g + l * 1024, ln1b + l * 1024, xb, nullptr, nullptr);
    gemm128<0><<<dim3(24, 32), 256, 0, stream>>>(xb, wqT, bqkv + l * 3072, qkv, nullptr, nullptr, 4096, 3072, 1024);
    rope_kernel<<<8192, 256, 0, stream>>>(qkv, pid, qhp, khp, vhp);
    attn_mfma<<<dim3(16, 16, 4), 256, 0, stream>>>(qhp, khp, vhp, maskf, xb);
    gemm128<1><<<dim3(8, 32), 256, 0, stream>>>(xb, woT, bo + l * 1024, h, nullptr, nullptr, 4096, 1024, 1024);
    ln_kernel<0><<<4096, 256, 0, stream>>>(h, ln2g + l * 1024, ln2b + l * 1024, xb, nullptr, nullptr);
    gemm128<2><<<dim3(32, 32), 256, 0, stream>>>(xb, wfT, bfc + l * 4096, nullptr, ffb, nullptr, 4096, 4096, 1024);
    gemm128<3><<<dim3(8, 32), 256, 0, stream>>>(ffb, wpT, bpj + l * 1024, h, nullptr, maskf, 4096, 1024, 4096);
  }
  ln_kernel<1><<<4096, 256, 0, stream>>>(h, lnfg, lnfb, nullptr, out, maskf);
}

// Round 4
// 1488.840 us; speedup vs baseline: 3.7046x; 1.0736x over previous
//
#include <hip/hip_runtime.h>
#include <math.h>

// L=4, H=1024, NH=16, HD=64, FF=4096, B=4, S=1024
// ws layout (~129 MB): h fp32 16MB | qkv fp32 48MB | xb bf16 8MB | ffb bf16 32MB
//   (ffb region doubles as qh/kh/vh bf16 head-major between rope and attn) |
//   wqT 6MB | woT 2MB | wfT 8MB | wpT 8MB | maskf 16KB | pid 16KB

typedef unsigned short u16;
typedef unsigned int u32;
typedef __attribute__((ext_vector_type(8))) short short8;
typedef __attribute__((ext_vector_type(4))) float f32x4;
typedef __attribute__((ext_vector_type(4))) u16 u16x4;

#define NEGV (-3.402823466e38f)

__device__ __forceinline__ u16 f2bf(float f) {
  union { float f; u32 u; } v; v.f = f;
  u32 r = v.u + 0x7FFFu + ((v.u >> 16) & 1u);
  return (u16)(r >> 16);
}

__device__ __forceinline__ float gelu_tanh(float x) {
  float z = 0.7978845608028654f * (x + 0.044715f * x * x * x);
  z = fmaxf(fminf(z, 30.f), -30.f);
  float t = __expf(2.f * z);
  return 0.5f * x * (1.f + (t - 1.f) / (t + 1.f));
}

// async 16B global -> LDS. Per-lane dest pointer must be affine base + lane*16
// (HW scatters lane i to uniform-base + i*16; no arbitrary per-lane scatter).
__device__ __forceinline__ void gld_lds16(const u16* g, u16* l) {
  __builtin_amdgcn_global_load_lds((const __attribute__((address_space(1))) u32*)g,
                                   (__attribute__((address_space(3))) u32*)l, 16, 0, 0);
}

// ---------------- mask / position ids ----------------
__global__ __launch_bounds__(1024) void mask_pid_kernel(const void* __restrict__ maskp,
                                                        float* __restrict__ maskf,
                                                        int* __restrict__ pid) {
  int b = blockIdx.x, s = threadIdx.x;
  const u32* wp = (const u32*)maskp;
  bool int_mode = ((wp[0] & 0xFFFFFF00u) == 0u);
  int mv;
  if (int_mode) mv = (((const int*)maskp)[b * 1024 + s] != 0) ? 1 : 0;
  else          mv = (((const unsigned char*)maskp)[b * 1024 + s] != 0) ? 1 : 0;
  __shared__ int sc[1024];
  sc[s] = mv;
  __syncthreads();
  for (int off = 1; off < 1024; off <<= 1) {
    int add = (s >= off) ? sc[s - off] : 0;
    __syncthreads();
    sc[s] += add;
    __syncthreads();
  }
  pid[b * 1024 + s] = mv ? (sc[s] - 1) : 0;
  maskf[b * 1024 + s] = (float)mv;
}

// ---------------- h = embeds * maskf ----------------
__global__ __launch_bounds__(256) void embed_kernel(const float* __restrict__ e,
                                                    const float* __restrict__ maskf,
                                                    float* __restrict__ h) {
  int idx = blockIdx.x * 256 + threadIdx.x;
  size_t o = (size_t)idx * 4;
  int row = (int)(o >> 10);
  float mf = maskf[row];
  float4 v = *(const float4*)(e + o);
  float4 r; r.x = v.x * mf; r.y = v.y * mf; r.z = v.z * mf; r.w = v.w * mf;
  *(float4*)(h + o) = r;
}

// ---------------- transpose fp32 [K][N] -> bf16 [N][K] ----------------
__global__ __launch_bounds__(256) void transpose_bf16(const float* __restrict__ in,
                                                      u16* __restrict__ out,
                                                      int K, int N) {
  __shared__ float t[32][33];
  int tx = threadIdx.x, ty = threadIdx.y;
  int n0 = blockIdx.x * 32, k0 = blockIdx.y * 32;
#pragma unroll
  for (int j = 0; j < 4; ++j) {
    int k = ty + j * 8;
    t[k][tx] = in[(size_t)(k0 + k) * N + n0 + tx];
  }
  __syncthreads();
#pragma unroll
  for (int j = 0; j < 4; ++j) {
    int n = ty + j * 8;
    out[(size_t)(n0 + n) * K + k0 + tx] = f2bf(t[tx][n]);
  }
}

// ---------------- layernorm (H=1024) ----------------
template <int MODE>
__global__ __launch_bounds__(256) void ln_kernel(const float* __restrict__ x,
                                                 const float* __restrict__ g,
                                                 const float* __restrict__ bb,
                                                 u16* __restrict__ yb,
                                                 float* __restrict__ yf,
                                                 const float* __restrict__ maskf) {
  int row = blockIdx.x, tid = threadIdx.x;
  const float* xr = x + (size_t)row * 1024;
  float4 v = *(const float4*)(xr + tid * 4);
  float s = v.x + v.y + v.z + v.w;
  float q = v.x * v.x + v.y * v.y + v.z * v.z + v.w * v.w;
#pragma unroll
  for (int off = 32; off >= 1; off >>= 1) {
    s += __shfl_xor(s, off);
    q += __shfl_xor(q, off);
  }
  __shared__ float ps[4], pq[4];
  int w = tid >> 6, lane = tid & 63;
  if (lane == 0) { ps[w] = s; pq[w] = q; }
  __syncthreads();
  float S = ps[0] + ps[1] + ps[2] + ps[3];
  float Q = pq[0] + pq[1] + pq[2] + pq[3];
  float mean = S * (1.f / 1024.f);
  float var = fmaxf(Q * (1.f / 1024.f) - mean * mean, 0.f);
  float rstd = rsqrtf(var + 1e-5f);
  int c = tid * 4;
  float4 gv = *(const float4*)(g + c);
  float4 bv = *(const float4*)(bb + c);
  float y0 = (v.x - mean) * rstd * gv.x + bv.x;
  float y1 = (v.y - mean) * rstd * gv.y + bv.y;
  float y2 = (v.z - mean) * rstd * gv.z + bv.z;
  float y3 = (v.w - mean) * rstd * gv.w + bv.w;
  if (MODE == 0) {
    u16x4 o; o.x = f2bf(y0); o.y = f2bf(y1); o.z = f2bf(y2); o.w = f2bf(y3);
    *(u16x4*)(yb + (size_t)row * 1024 + c) = o;
  } else {
    float mf = maskf[row];
    float4 o; o.x = y0 * mf; o.y = y1 * mf; o.z = y2 * mf; o.w = y3 * mf;
    *(float4*)(yf + (size_t)row * 1024 + c) = o;
  }
}

// ---------------- 128x128 bf16 MFMA GEMM, XCD-banded + LDS dbuf ----------------
// C[M,N] = A[M,K] @ Bt[N,K]^T + bias. REQUIRES M == 4096 (Mt=32 -> 4 m-tiles/XCD).
// Linear grid of (N/128)*32 blocks. Decode (assuming dispatch XCD = bid%8):
//   xcd = bid&7 owns m-tiles [xcd*4, xcd*4+4); s=bid>>3 sweeps nt-major, mt inner,
//   so the 4 concurrently-dispatched blocks of an XCD share one B-tile and the
//   1MB A-band stays hot in that XCD's L2. Per-XCD fetch ~ A/8 + B (vs A + B).
// LDS: double-buffered 2x(8+8)KB. Bank swizzle: source k-group XOR'd with
// (row>>1)&3 so b128 frag reads spread over banks (8-way -> 2-way, free).
// EPI 0: Of = v   1: Of += v   2: Ob = bf16(gelu(v))   3: Of = (Of+v)*maskf[row]
template <int EPI>
__global__ __launch_bounds__(256) void gemm128(const u16* __restrict__ A,
                                               const u16* __restrict__ Bt,
                                               const float* __restrict__ bias,
                                               float* __restrict__ Of,
                                               u16* __restrict__ Ob,
                                               const float* __restrict__ maskf,
                                               int M, int N, int K) {
  __shared__ __align__(16) u16 As[2][128 * 32];
  __shared__ __align__(16) u16 Bs[2][128 * 32];
  const int tid = threadIdx.x;
  const int lane = tid & 63, w = tid >> 6;
  const int wm = w >> 1, wn = w & 1;
  const int bid = blockIdx.x;
  const int m0 = (((bid & 7) << 2) + ((bid >> 3) & 3)) << 7;  // XCD band, mt inner
  const int n0 = (bid >> 5) << 7;                              // nt outer (streamed)
  const int ln = lane & 15, kg = lane >> 4;
  const int kxor = (kg ^ ((ln >> 1) & 3)) * 8;  // bank-spread column group

  f32x4 acc[4][4] = {};

  // staging: thread tid owns LDS slot (row tid>>2, colgroup tid&3) [+ row 64].
  // Source column group is XOR-swizzled so reads are conflict-free.
  const int r0 = tid >> 2;
  const int gsw = ((tid & 3) ^ ((tid >> 3) & 3)) * 8;
  const u16* Ap0 = A + (size_t)(m0 + r0) * K + gsw;
  const u16* Ap1 = A + (size_t)(m0 + 64 + r0) * K + gsw;
  const u16* Bp0 = Bt + (size_t)(n0 + r0) * K + gsw;
  const u16* Bp1 = Bt + (size_t)(n0 + 64 + r0) * K + gsw;

  const int niter = K >> 5;
  // prologue: stage tile 0 into buffer 0
  gld_lds16(Ap0, &As[0][tid * 8]);
  gld_lds16(Ap1, &As[0][(tid + 256) * 8]);
  gld_lds16(Bp0, &Bs[0][tid * 8]);
  gld_lds16(Bp1, &Bs[0][(tid + 256) * 8]);

  for (int it = 0; it < niter; ++it) {
    __syncthreads();  // vmcnt(0) drain: buf[cur] ready; prev reads of buf[nxt] done
    const int cur = it & 1, nxt = cur ^ 1;
    if (it + 1 < niter) {
      const int k0 = (it + 1) << 5;
      gld_lds16(Ap0 + k0, &As[nxt][tid * 8]);
      gld_lds16(Ap1 + k0, &As[nxt][(tid + 256) * 8]);
      gld_lds16(Bp0 + k0, &Bs[nxt][tid * 8]);
      gld_lds16(Bp1 + k0, &Bs[nxt][(tid + 256) * 8]);
    }
    short8 af[4], bfr[4];
#pragma unroll
    for (int i = 0; i < 4; ++i)
      af[i] = *(const short8*)(&As[cur][(wm * 64 + i * 16 + ln) * 32 + kxor]);
#pragma unroll
    for (int i = 0; i < 4; ++i)
      bfr[i] = *(const short8*)(&Bs[cur][(wn * 64 + i * 16 + ln) * 32 + kxor]);
#pragma unroll
    for (int i = 0; i < 4; ++i)
#pragma unroll
      for (int j = 0; j < 4; ++j)
        acc[i][j] = __builtin_amdgcn_mfma_f32_16x16x32_bf16(af[i], bfr[j], acc[i][j], 0, 0, 0);
  }

#pragma unroll
  for (int i = 0; i < 4; ++i) {
#pragma unroll
    for (int j = 0; j < 4; ++j) {
      int col = n0 + wn * 64 + j * 16 + ln;
      float bvv = bias[col];
#pragma unroll
      for (int rr = 0; rr < 4; ++rr) {
        int row = m0 + wm * 64 + i * 16 + kg * 4 + rr;
        size_t idx = (size_t)row * N + col;
        float v = acc[i][j][rr] + bvv;
        if (EPI == 0) {
          Of[idx] = v;
        } else if (EPI == 1) {
          Of[idx] += v;
        } else if (EPI == 2) {
          Ob[idx] = f2bf(gelu_tanh(v));
        } else {
          Of[idx] = (Of[idx] + v) * maskf[row];
        }
      }
    }
  }
}

// ---------------- RoPE: qkv fp32 [4096][3072] -> bf16 head-major q,k,v [B*NH*S][64] --------
__global__ __launch_bounds__(256) void rope_kernel(const float* __restrict__ qkv,
                                                   const int* __restrict__ pid,
                                                   u16* __restrict__ qh,
                                                   u16* __restrict__ kh,
                                                   u16* __restrict__ vh) {
  int idx = blockIdx.x * 256 + threadIdx.x;  // 4096*16*32
  int i = idx & 31;
  int hh = (idx >> 5) & 15;
  int row = idx >> 9;
  int b = row >> 10, s = row & 1023;
  float p = (float)pid[row];
  float inv = __expf(-(float)(2 * i) * (9.210340371976184f / 64.f));
  float th = p * inv;
  float c = cosf(th), sn = sinf(th);
  size_t base = (size_t)row * 3072 + hh * 64 + 2 * i;
  float q0 = qkv[base], q1 = qkv[base + 1];
  float k0 = qkv[base + 1024], k1 = qkv[base + 1025];
  float v0 = qkv[base + 2048], v1 = qkv[base + 2049];
  float qr0 = (q0 * c - q1 * sn) * 0.125f;
  float qr1 = (q1 * c + q0 * sn) * 0.125f;
  float kr0 = k0 * c - k1 * sn;
  float kr1 = k1 * c + k0 * sn;
  size_t hbase = ((size_t)(b * 16 + hh) * 1024 + s) * 64 + 2 * i;
  *(u32*)(qh + hbase) = (u32)f2bf(qr0) | ((u32)f2bf(qr1) << 16);
  *(u32*)(kh + hbase) = (u32)f2bf(kr0) | ((u32)f2bf(kr1) << 16);
  *(u32*)(vh + hbase) = (u32)f2bf(v0) | ((u32)f2bf(v1) << 16);
}

// ---------------- MFMA flash attention ----------------
__global__ __launch_bounds__(256) void attn_mfma(const u16* __restrict__ qh,
                                                 const u16* __restrict__ kh,
                                                 const u16* __restrict__ vh,
                                                 const float* __restrict__ maskf,
                                                 u16* __restrict__ ctx) {
  const int b = blockIdx.z, h = blockIdx.y, qt = blockIdx.x;
  const int tid = threadIdx.x, lane = tid & 63, w = tid >> 6;
  const int ln = lane & 15, kg = lane >> 4;
  const int q0 = qt * 64;
  const size_t hb = (size_t)(b * 16 + h) * 1024 * 64;

  __shared__ __align__(16) u16 Ks[64][72];
  __shared__ __align__(16) u16 VsT[64][72];  // [d][key]
  __shared__ __align__(16) u16 Ps[64][72];   // [q local][key]
  __shared__ float Ms[64];

  const int qrow = q0 + w * 16 + ln;
  short8 qa0 = *(const short8*)(qh + hb + (size_t)qrow * 64 + kg * 8);
  short8 qa1 = *(const short8*)(qh + hb + (size_t)qrow * 64 + 32 + kg * 8);

  f32x4 Oc[4] = {};
  float m_i[4], l_i[4];
#pragma unroll
  for (int r = 0; r < 4; ++r) { m_i[r] = NEGV; l_i[r] = 0.f; }

  const int ntiles = qt + 1;
  for (int t = 0; t < ntiles; ++t) {
    __syncthreads();
    {
      int row = tid >> 2, c8 = (tid & 3) * 8;
      const u16* kp2 = kh + hb + (size_t)(t * 64 + row) * 64;
      *(uint4*)(&Ks[row][c8]) = *(const uint4*)(kp2 + c8);
      *(uint4*)(&Ks[row][c8 + 32]) = *(const uint4*)(kp2 + c8 + 32);
    }
    {
      int kp = tid >> 3, dg = tid & 7;
      const u16* vp0 = vh + hb + (size_t)(t * 64 + 2 * kp) * 64 + dg * 8;
      uint4 r0 = *(const uint4*)vp0;
      uint4 r1 = *(const uint4*)(vp0 + 64);
      u32 a0[4] = {r0.x, r0.y, r0.z, r0.w};
      u32 a1[4] = {r1.x, r1.y, r1.z, r1.w};
#pragma unroll
      for (int j = 0; j < 8; ++j) {
        u32 lo = (a0[j >> 1] >> (16 * (j & 1))) & 0xffffu;
        u32 hi = (a1[j >> 1] >> (16 * (j & 1))) & 0xffffu;
        *(u32*)(&VsT[dg * 8 + j][2 * kp]) = lo | (hi << 16);
      }
    }
    if (tid < 64) Ms[tid] = maskf[b * 1024 + t * 64 + tid];
    __syncthreads();

    f32x4 Sc[4];
#pragma unroll
    for (int c = 0; c < 4; ++c) {
      short8 kb0 = *(const short8*)(&Ks[c * 16 + ln][kg * 8]);
      short8 kb1 = *(const short8*)(&Ks[c * 16 + ln][32 + kg * 8]);
      f32x4 z = {};
      z = __builtin_amdgcn_mfma_f32_16x16x32_bf16(qa0, kb0, z, 0, 0, 0);
      Sc[c] = __builtin_amdgcn_mfma_f32_16x16x32_bf16(qa1, kb1, z, 0, 0, 0);
    }
    float mk[4];
#pragma unroll
    for (int c = 0; c < 4; ++c) mk[c] = Ms[c * 16 + ln];

#pragma unroll
    for (int r = 0; r < 4; ++r) {
      int qg = q0 + w * 16 + kg * 4 + r;
      float vmax = NEGV;
#pragma unroll
      for (int c = 0; c < 4; ++c) {
        int key = t * 64 + c * 16 + ln;
        bool valid = (key <= qg) && (mk[c] != 0.f);
        float sv = valid ? Sc[c][r] : NEGV;
        Sc[c][r] = sv;
        vmax = fmaxf(vmax, sv);
      }
#pragma unroll
      for (int off = 1; off <= 8; off <<= 1) vmax = fmaxf(vmax, __shfl_xor(vmax, off));
      float mnew = fmaxf(m_i[r], vmax);
      float alpha = __expf(m_i[r] - mnew);
      m_i[r] = mnew;
      float ls = 0.f;
#pragma unroll
      for (int c = 0; c < 4; ++c) {
        float p = __expf(Sc[c][r] - mnew);
        Sc[c][r] = p;
        ls += p;
      }
#pragma unroll
      for (int off = 1; off <= 8; off <<= 1) ls += __shfl_xor(ls, off);
      l_i[r] = l_i[r] * alpha + ls;
#pragma unroll
      for (int c = 0; c < 4; ++c) Oc[c][r] *= alpha;
#pragma unroll
      for (int c = 0; c < 4; ++c) Ps[w * 16 + kg * 4 + r][c * 16 + ln] = f2bf(Sc[c][r]);
    }
    __syncthreads();

    short8 pa0 = *(const short8*)(&Ps[w * 16 + ln][kg * 8]);
    short8 pa1 = *(const short8*)(&Ps[w * 16 + ln][32 + kg * 8]);
#pragma unroll
    for (int c = 0; c < 4; ++c) {
      short8 vb0 = *(const short8*)(&VsT[c * 16 + ln][kg * 8]);
      short8 vb1 = *(const short8*)(&VsT[c * 16 + ln][32 + kg * 8]);
      Oc[c] = __builtin_amdgcn_mfma_f32_16x16x32_bf16(pa0, vb0, Oc[c], 0, 0, 0);
      Oc[c] = __builtin_amdgcn_mfma_f32_16x16x32_bf16(pa1, vb1, Oc[c], 0, 0, 0);
    }
  }

#pragma unroll
  for (int r = 0; r < 4; ++r) {
    float rl = 1.f / l_i[r];
    int row = q0 + w * 16 + kg * 4 + r;
#pragma unroll
    for (int c = 0; c < 4; ++c) {
      ctx[(size_t)(b * 1024 + row) * 1024 + h * 64 + c * 16 + ln] = f2bf(Oc[c][r] * rl);
    }
  }
}

// ---------------- launcher ----------------
extern "C" void kernel_launch(void* const* d_in, const int* in_sizes, int n_in,
                              void* d_out, int out_size, void* d_ws, size_t ws_size,
                              hipStream_t stream) {
  const float* embeds = (const float*)d_in[0];
  const void* amask   = d_in[1];
  const float* Wqkv = (const float*)d_in[2];
  const float* bqkv = (const float*)d_in[3];
  const float* Wo   = (const float*)d_in[4];
  const float* bo   = (const float*)d_in[5];
  const float* ln1g = (const float*)d_in[6];
  const float* ln1b = (const float*)d_in[7];
  const float* ln2g = (const float*)d_in[8];
  const float* ln2b = (const float*)d_in[9];
  const float* Wfc  = (const float*)d_in[10];
  const float* bfc  = (const float*)d_in[11];
  const float* Wpj  = (const float*)d_in[12];
  const float* bpj  = (const float*)d_in[13];
  const float* lnfg = (const float*)d_in[14];
  const float* lnfb = (const float*)d_in[15];
  float* out = (float*)d_out;

  char* ws = (char*)d_ws;
  float* h     = (float*)(ws);                            // 16 MB
  float* qkv   = (float*)(ws + (size_t)(16u << 20));      // 48 MB
  u16*   xb    = (u16*)(ws + (size_t)(64u << 20));        // 8 MB
  u16*   ffb   = (u16*)(ws + (size_t)(72u << 20));        // 32 MB (also qh/kh/vh)
  u16*   qhp   = (u16*)(ws + (size_t)(72u << 20));        // 8 MB
  u16*   khp   = (u16*)(ws + (size_t)(80u << 20));        // 8 MB
  u16*   vhp   = (u16*)(ws + (size_t)(88u << 20));        // 8 MB
  u16*   wqT   = (u16*)(ws + (size_t)(104u << 20));       // 6 MB
  u16*   woT   = (u16*)(ws + (size_t)(110u << 20));       // 2 MB
  u16*   wfT   = (u16*)(ws + (size_t)(112u << 20));       // 8 MB
  u16*   wpT   = (u16*)(ws + (size_t)(120u << 20));       // 8 MB
  float* maskf = (float*)(ws + (size_t)(128u << 20));
  int*   pid   = (int*)(ws + (size_t)(128u << 20) + (16u << 10));

  mask_pid_kernel<<<4, 1024, 0, stream>>>(amask, maskf, pid);
  embed_kernel<<<4096, 256, 0, stream>>>(embeds, maskf, h);

  for (int l = 0; l < 4; ++l) {
    transpose_bf16<<<dim3(96, 32), dim3(32, 8), 0, stream>>>(Wqkv + (size_t)l * 1024 * 3072, wqT, 1024, 3072);
    transpose_bf16<<<dim3(32, 32), dim3(32, 8), 0, stream>>>(Wo + (size_t)l * 1024 * 1024, woT, 1024, 1024);
    transpose_bf16<<<dim3(128, 32), dim3(32, 8), 0, stream>>>(Wfc + (size_t)l * 1024 * 4096, wfT, 1024, 4096);
    transpose_bf16<<<dim3(32, 128), dim3(32, 8), 0, stream>>>(Wpj + (size_t)l * 4096 * 1024, wpT, 4096, 1024);

    ln_kernel<0><<<4096, 256, 0, stream>>>(h, ln1g + l * 1024, ln1b + l * 1024, xb, nullptr, nullptr);
    gemm128<0><<<dim3(24 * 32), 256, 0, stream>>>(xb, wqT, bqkv + l * 3072, qkv, nullptr, nullptr, 4096, 3072, 1024);
    rope_kernel<<<8192, 256, 0, stream>>>(qkv, pid, qhp, khp, vhp);
    attn_mfma<<<dim3(16, 16, 4), 256, 0, stream>>>(qhp, khp, vhp, maskf, xb);
    gemm128<1><<<dim3(8 * 32), 256, 0, stream>>>(xb, woT, bo + l * 1024, h, nullptr, nullptr, 4096, 1024, 1024);
    ln_kernel<0><<<4096, 256, 0, stream>>>(h, ln2g + l * 1024, ln2b + l * 1024, xb, nullptr, nullptr);
    gemm128<2><<<dim3(32 * 32), 256, 0, stream>>>(xb, wfT, bfc + l * 4096, nullptr, ffb, nullptr, 4096, 4096, 1024);
    gemm128<3><<<dim3(8 * 32), 256, 0, stream>>>(ffb, wpT, bpj + l * 1024, h, nullptr, maskf, 4096, 1024, 4096);
  }
  ln_kernel<1><<<4096, 256, 0, stream>>>(h, lnfg, lnfb, nullptr, out, maskf);
}